// Round 7
// baseline (294.618 us; speedup 1.0000x reference)
//
#include <hip/hip_runtime.h>
#include <hip/hip_bf16.h>

#define B_  8
#define D_  128
#define K_  7
#define Q_  256
#define G0_ 511
#define G0P 512
#define G1_ 512
#define F1_ 512
#define F2_ 1024
#define OUT_ 16

typedef __bf16 bf16x8 __attribute__((ext_vector_type(8)));
typedef float  f32x4  __attribute__((ext_vector_type(4)));

// async global->LDS: one instruction = 64 lanes x 16B = 1KB.
#define GL2LDS(g, l) __builtin_amdgcn_global_load_lds(                        \
    (const __attribute__((address_space(1))) void*)(g),                       \
    (__attribute__((address_space(3))) void*)(l), 16, 0, 0)

// ---------------------------------------------------------------------------
// k_prep: fused preprocessing, 1320 blocks x 256 threads. (all R3-verified)
//  [0,1024):    u/v rows
//  [1024,1280): w1 -> swizzled bf16 w1t
//  [1280,1312): qterm
//  [1312,1320): zero xg
__global__ void k_prep(const float* __restrict__ x, const float* __restrict__ g0w,
                       const float* __restrict__ g0b, const float* __restrict__ qst,
                       const float* __restrict__ g1w, const float* __restrict__ g1b,
                       float* __restrict__ u, float* __restrict__ v,
                       __bf16* __restrict__ w1t, float* __restrict__ qterm,
                       float* __restrict__ xg) {
    const int blk = blockIdx.x;
    const int t   = threadIdx.x;
    if (blk < 1024) {
        __shared__ float xs[8];
        if (t < K_) xs[t] = x[blk * K_ + t];
        __syncthreads();
        #pragma unroll
        for (int h = 0; h < 2; ++h) {
            const int g = t + h * 256;
            float su = 0.f, sv = 0.f;
            if (g < G0_) {
                #pragma unroll
                for (int k = 0; k < K_; ++k) {
                    su += xs[k] * g0w[k * G0_ + g];
                    sv += xs[k] * g0w[(K_ + k) * G0_ + g];
                }
                su += g0b[g];
            }
            u[blk * G0P + g] = (g < G0_) ? su : 0.f;
            v[blk * G0P + g] = (g < G0_) ? sv : 0.f;
        }
    } else if (blk < 1280) {
        // R3-verified: w1t[kq*16384 + n*32 + slot*8 + j], slot = chunk^((n>>1)&3)
        __shared__ __bf16 tile[32][33];
        const int bb = blk - 1024;
        const int bx = bb & 15, by = bb >> 4;
        const int r = t >> 5, c = t & 31;
        #pragma unroll
        for (int i = 0; i < 4; ++i) {
            const int k = by * 32 + r + i * 8;
            const int n = bx * 32 + c;
            tile[r + i * 8][c] = (__bf16)((k < G0_) ? g1w[k * G1_ + n] : 0.f);
        }
        __syncthreads();
        #pragma unroll
        for (int i = 0; i < 4; ++i) {
            const int n = bx * 32 + r + i * 8;
            const int cc = (c >> 3) & 3, j = c & 7;
            const int slot = cc ^ ((n >> 1) & 3);
            w1t[by * 16384 + n * 32 + slot * 8 + j] = tile[c][r + i * 8];
        }
    } else if (blk < 1312) {
        __shared__ float qs[256];
        __shared__ float red[2][128];
        const int qb = blk - 1280;
        const int b = qb >> 2, nb = (qb & 3) << 7;
        qs[t] = qst[b * Q_ + t];
        __syncthreads();
        const int n = nb + (t & 127);
        const int qh = (t >> 7) * 128;
        float s = 0.f;
        #pragma unroll 8
        for (int q = 0; q < 128; ++q)
            s += qs[qh + q] * g1w[(G0_ + qh + q) * G1_ + n];
        red[t >> 7][t & 127] = s;
        __syncthreads();
        if (t < 128)
            qterm[b * G1_ + nb + t] = red[0][t] + red[1][t] + g1b[nb + t];
    } else {
        const int b = blk - 1312;
        xg[b * G1_ + t] = 0.f;
        xg[b * G1_ + 256 + t] = 0.f;
    }
}

// ---------------------------------------------------------------------------
// k_pair: block = (b, a-pair p, nhalf). M=256 (a0,a1 x 128 c), N=256, K=512.
// Each wave computes a 128x128 register tile (acc[8][8], 256 AGPR, 1 wave/SIMD).
// A = relu(u[c]+v_a) staged in LDS fragment order; v reads are wave-uniform
// LDS broadcasts (waves 0,1 -> a0; waves 2,3 -> a1). B DMA'd from swizzled w1t.
__global__ __launch_bounds__(256, 1)
void k_pair(const float* __restrict__ u, const float* __restrict__ v,
            const __bf16* __restrict__ w1t, const float* __restrict__ qterm,
            float* __restrict__ xg) {
    __shared__ float  v_a[1024];       // [am(2)][512]
    __shared__ __bf16 At[2][8192];     // [buf][mtile(16)][lane(64)*8]
    __shared__ __bf16 Bt[2][8192];     // [buf][n_local(256)][32 swizzled]
    __shared__ float  ebuf[4][128];

    const int bid  = blockIdx.x;       // [0,1024)
    const int b    = bid >> 7;
    const int p    = (bid >> 1) & 63;  // a-pair: a0=2p, a1=2p+1
    const int nbase = (bid & 1) << 8;
    const int tid  = threadIdx.x;
    const int wave = tid >> 6, lane = tid & 63;
    const int quad = lane >> 4, l15 = lane & 15;
    const int wm = wave & 1, wn = wave >> 1;
    const int nloc = wn * 128;
    const int swz  = (l15 >> 1) & 3;

    // v rows for a0, a1 (256 threads x float4 = 1024 floats)
    *(float4*)(v_a + tid * 4) =
        *(const float4*)(v + (b * D_ + 2 * p + (tid >> 7)) * G0P + (tid & 127) * 4);

    // B staging: verbatim R3 geometry (4 DMA instrs/wave, 16 KB/kq total)
    const int iw0 = wave * 4;
    const __bf16* gsrc = w1t + (size_t)(nbase + iw0 * 16 + (lane >> 2)) * 32
                             + (lane & 3) * 8;

    // A staging: thread stages m = tid (am = tid>>7, c = tid&127), all 32 k.
    const int am = tid >> 7;
    const float* urow = u + (b * D_ + (tid & 127)) * G0P;
    const int woff = (tid >> 4) * 512 + (tid & 15) * 8;   // + chunk*128

    f32x4 acc[8][8];
    #pragma unroll
    for (int mt = 0; mt < 8; ++mt)
        #pragma unroll
        for (int nt = 0; nt < 8; ++nt)
            acc[mt][nt] = (f32x4){0.f, 0.f, 0.f, 0.f};

    float4 up[8];
    auto load_u = [&](int kq) {
        const float* pp = urow + kq * 32;
        #pragma unroll
        for (int j = 0; j < 8; ++j) up[j] = *(const float4*)(pp + j * 4);
    };
    auto stage_B = [&](int buf, int kq) {
        const __bf16* g = gsrc + kq * 16384;
        __bf16* l = &Bt[buf][iw0 * 512];
        #pragma unroll
        for (int j = 0; j < 4; ++j)
            GL2LDS(g + j * 512, l + j * 512);
    };
    auto write_A = [&](int buf, int kq) {
        const float* vp = v_a + am * 512 + kq * 32;   // wave-uniform -> broadcast
        #pragma unroll
        for (int q = 0; q < 4; ++q) {
            const float4 va = *(const float4*)(vp + q * 8);
            const float4 vb = *(const float4*)(vp + q * 8 + 4);
            const float4 ua = up[q * 2], ub = up[q * 2 + 1];
            bf16x8 h;
            h[0] = (__bf16)fmaxf(ua.x + va.x, 0.f);
            h[1] = (__bf16)fmaxf(ua.y + va.y, 0.f);
            h[2] = (__bf16)fmaxf(ua.z + va.z, 0.f);
            h[3] = (__bf16)fmaxf(ua.w + va.w, 0.f);
            h[4] = (__bf16)fmaxf(ub.x + vb.x, 0.f);
            h[5] = (__bf16)fmaxf(ub.y + vb.y, 0.f);
            h[6] = (__bf16)fmaxf(ub.z + vb.z, 0.f);
            h[7] = (__bf16)fmaxf(ub.w + vb.w, 0.f);
            *(bf16x8*)&At[buf][woff + q * 128] = h;
        }
    };

    // prologue
    stage_B(0, 0);
    load_u(0);
    __syncthreads();               // v_a visible, Bt[0] DMA drained
    write_A(0, 0);
    __syncthreads();               // At[0] visible

    for (int kq = 0; kq < 16; ++kq) {
        const int buf = kq & 1;
        if (kq < 15) {
            stage_B(buf ^ 1, kq + 1);
            load_u(kq + 1);
        }
        bf16x8 af[8], bfr[8];
        #pragma unroll
        for (int mt = 0; mt < 8; ++mt)
            af[mt] = *(const bf16x8*)&At[buf][(wm * 8 + mt) * 512 + lane * 8];
        const __bf16* btb = &Bt[buf][(nloc + l15) * 32 + ((quad ^ swz) << 3)];
        #pragma unroll
        for (int nt = 0; nt < 8; ++nt)
            bfr[nt] = *(const bf16x8*)(btb + nt * 512);
        #pragma unroll
        for (int mt = 0; mt < 8; ++mt)
            #pragma unroll
            for (int nt = 0; nt < 8; ++nt)
                acc[mt][nt] = __builtin_amdgcn_mfma_f32_16x16x32_bf16(
                    af[mt], bfr[nt], acc[mt][nt], 0, 0, 0);
        if (kq < 15) write_A(buf ^ 1, kq + 1);
        __syncthreads();
    }

    // epilogue: relu(C + qterm), sum 128 m-rows per wave, combine wm pairs, atomic
    #pragma unroll
    for (int nt = 0; nt < 8; ++nt) {
        const float q = qterm[b * G1_ + nbase + nloc + nt * 16 + l15];
        float s = 0.f;
        #pragma unroll
        for (int mt = 0; mt < 8; ++mt)
            #pragma unroll
            for (int r = 0; r < 4; ++r)
                s += fmaxf(acc[mt][nt][r] + q, 0.f);
        s += __shfl_xor(s, 16, 64);
        s += __shfl_xor(s, 32, 64);
        if (quad == 0) ebuf[wave][nt * 16 + l15] = s;
    }
    __syncthreads();
    {
        const int grp = tid >> 7, nl = tid & 127;
        atomicAdd(xg + b * G1_ + nbase + grp * 128 + nl,
                  ebuf[grp * 2][nl] + ebuf[grp * 2 + 1][nl]);
    }
}

// ---------------------------------------------------------------------------
// k_tail: whole f-MLP + log_softmax, 8 blocks (one per batch), block-local
// via LDS, original (k-major) weight layouts -> coalesced o-major reads.
__global__ __launch_bounds__(256)
void k_tail(const float* __restrict__ xg,
            const float* __restrict__ f1w, const float* __restrict__ f1b,
            const float* __restrict__ f2w, const float* __restrict__ f2b,
            const float* __restrict__ f3w, const float* __restrict__ f3b,
            float* __restrict__ out) {
    const int b = blockIdx.x, t = threadIdx.x;
    __shared__ float xs[G1_];
    __shared__ float s1[F1_];
    __shared__ float s2[F2_];
    __shared__ float red[16][17];
    __shared__ float lg[16];
    xs[t] = xg[b * G1_ + t];
    xs[t + 256] = xg[b * G1_ + 256 + t];
    __syncthreads();
    // f1: 512 outs, thread t -> o = t, t+256
    {
        float a0 = f1b[t], a1 = f1b[t + 256];
        #pragma unroll 8
        for (int k = 0; k < G1_; ++k) {
            const float xv = xs[k];
            a0 += xv * f1w[k * F1_ + t];
            a1 += xv * f1w[k * F1_ + t + 256];
        }
        s1[t] = fmaxf(a0, 0.f);
        s1[t + 256] = fmaxf(a1, 0.f);
    }
    __syncthreads();
    // f2: 1024 outs, thread t -> o = 4t..4t+3 (float4 coalesced)
    {
        float4 a = *(const float4*)(f2b + t * 4);
        #pragma unroll 8
        for (int k = 0; k < F1_; ++k) {
            const float sv = s1[k];
            const float4 w = *(const float4*)(f2w + k * F2_ + t * 4);
            a.x += sv * w.x; a.y += sv * w.y; a.z += sv * w.z; a.w += sv * w.w;
        }
        float4 r;
        r.x = fmaxf(a.x, 0.f); r.y = fmaxf(a.y, 0.f);
        r.z = fmaxf(a.z, 0.f); r.w = fmaxf(a.w, 0.f);
        *(float4*)(s2 + t * 4) = r;
    }
    __syncthreads();
    // f3: 16 outs, thread t -> (o = t&15, k-slice (t>>4)*64)
    {
        const int o = t & 15, ks = (t >> 4) * 64;
        float a = 0.f;
        #pragma unroll 8
        for (int j = 0; j < 64; ++j)
            a += s2[ks + j] * f3w[(ks + j) * OUT_ + o];
        red[t >> 4][o] = a;
    }
    __syncthreads();
    if (t < 16) {
        float a = f3b[t];
        #pragma unroll
        for (int i = 0; i < 16; ++i) a += red[i][t];
        lg[t] = a;
    }
    __syncthreads();
    if (t < 16) {
        float m = -1e30f;
        #pragma unroll
        for (int i = 0; i < 16; ++i) m = fmaxf(m, lg[i]);
        float se = 0.f;
        #pragma unroll
        for (int i = 0; i < 16; ++i) se += __expf(lg[i] - m);
        out[b * OUT_ + t] = lg[t] - m - logf(se);
    }
}

// ---------------------------------------------------------------------------
extern "C" void kernel_launch(void* const* d_in, const int* in_sizes, int n_in,
                              void* d_out, int out_size, void* d_ws, size_t ws_size,
                              hipStream_t stream) {
    const float* x   = (const float*)d_in[0];
    const float* qst = (const float*)d_in[1];
    const float* g0w = (const float*)d_in[2];
    const float* g0b = (const float*)d_in[3];
    const float* g1w = (const float*)d_in[4];
    const float* g1b = (const float*)d_in[5];
    const float* f1w = (const float*)d_in[6];
    const float* f1b = (const float*)d_in[7];
    const float* f2w = (const float*)d_in[8];
    const float* f2b = (const float*)d_in[9];
    const float* f3w = (const float*)d_in[10];
    const float* f3b = (const float*)d_in[11];

    char* ws = (char*)d_ws;
    float*  u     = (float*)ws;  ws += (size_t)B_ * D_ * G0P * 4;   // 2 MB
    float*  v     = (float*)ws;  ws += (size_t)B_ * D_ * G0P * 4;   // 2 MB
    __bf16* w1t   = (__bf16*)ws; ws += (size_t)G1_ * G0P * 2;       // 512 KB
    float*  qterm = (float*)ws;  ws += (size_t)B_ * G1_ * 4;
    float*  xg    = (float*)ws;  ws += (size_t)B_ * G1_ * 4;

    k_prep<<<1320, 256, 0, stream>>>(x, g0w, g0b, qst, g1w, g1b,
                                     u, v, w1t, qterm, xg);
    k_pair<<<1024, 256, 0, stream>>>(u, v, w1t, qterm, xg);
    k_tail<<<B_, 256, 0, stream>>>(xg, f1w, f1b, f2w, f2b, f3w, f3b,
                                   (float*)d_out);
}

// Round 8
// 215.676 us; speedup vs baseline: 1.3660x; 1.3660x over previous
//
#include <hip/hip_runtime.h>
#include <hip/hip_bf16.h>

#define B_  8
#define D_  128
#define K_  7
#define Q_  256
#define G0_ 511
#define G0P 512
#define G1_ 512
#define F1_ 512
#define F2_ 1024
#define OUT_ 16

typedef __bf16 bf16x8 __attribute__((ext_vector_type(8)));
typedef float  f32x4  __attribute__((ext_vector_type(4)));

// async global->LDS: one instruction = 64 lanes x 16B = 1KB.
#define GL2LDS(g, l) __builtin_amdgcn_global_load_lds(                        \
    (const __attribute__((address_space(1))) void*)(g),                       \
    (__attribute__((address_space(3))) void*)(l), 16, 0, 0)

// ---------------------------------------------------------------------------
// k_prep: fused preprocessing, 1320 blocks x 256 threads. (all R3-verified)
//  [0,1024):    u/v rows
//  [1024,1280): w1 -> swizzled bf16 w1t
//  [1280,1312): qterm
//  [1312,1320): zero xg
__global__ void k_prep(const float* __restrict__ x, const float* __restrict__ g0w,
                       const float* __restrict__ g0b, const float* __restrict__ qst,
                       const float* __restrict__ g1w, const float* __restrict__ g1b,
                       float* __restrict__ u, float* __restrict__ v,
                       __bf16* __restrict__ w1t, float* __restrict__ qterm,
                       float* __restrict__ xg) {
    const int blk = blockIdx.x;
    const int t   = threadIdx.x;
    if (blk < 1024) {
        __shared__ float xs[8];
        if (t < K_) xs[t] = x[blk * K_ + t];
        __syncthreads();
        #pragma unroll
        for (int h = 0; h < 2; ++h) {
            const int g = t + h * 256;
            float su = 0.f, sv = 0.f;
            if (g < G0_) {
                #pragma unroll
                for (int k = 0; k < K_; ++k) {
                    su += xs[k] * g0w[k * G0_ + g];
                    sv += xs[k] * g0w[(K_ + k) * G0_ + g];
                }
                su += g0b[g];
            }
            u[blk * G0P + g] = (g < G0_) ? su : 0.f;
            v[blk * G0P + g] = (g < G0_) ? sv : 0.f;
        }
    } else if (blk < 1280) {
        // R3-verified: w1t[kq*16384 + n*32 + slot*8 + j], slot = chunk^((n>>1)&3)
        __shared__ __bf16 tile[32][33];
        const int bb = blk - 1024;
        const int bx = bb & 15, by = bb >> 4;
        const int r = t >> 5, c = t & 31;
        #pragma unroll
        for (int i = 0; i < 4; ++i) {
            const int k = by * 32 + r + i * 8;
            const int n = bx * 32 + c;
            tile[r + i * 8][c] = (__bf16)((k < G0_) ? g1w[k * G1_ + n] : 0.f);
        }
        __syncthreads();
        #pragma unroll
        for (int i = 0; i < 4; ++i) {
            const int n = bx * 32 + r + i * 8;
            const int cc = (c >> 3) & 3, j = c & 7;
            const int slot = cc ^ ((n >> 1) & 3);
            w1t[by * 16384 + n * 32 + slot * 8 + j] = tile[c][r + i * 8];
        }
    } else if (blk < 1312) {
        __shared__ float qs[256];
        __shared__ float red[2][128];
        const int qb = blk - 1280;
        const int b = qb >> 2, nb = (qb & 3) << 7;
        qs[t] = qst[b * Q_ + t];
        __syncthreads();
        const int n = nb + (t & 127);
        const int qh = (t >> 7) * 128;
        float s = 0.f;
        #pragma unroll 8
        for (int q = 0; q < 128; ++q)
            s += qs[qh + q] * g1w[(G0_ + qh + q) * G1_ + n];
        red[t >> 7][t & 127] = s;
        __syncthreads();
        if (t < 128)
            qterm[b * G1_ + nb + t] = red[0][t] + red[1][t] + g1b[nb + t];
    } else {
        const int b = blk - 1312;
        xg[b * G1_ + t] = 0.f;
        xg[b * G1_ + 256 + t] = 0.f;
    }
}

// ---------------------------------------------------------------------------
// k_pair: R3-VERIFIED core (16x16x32 MFMA). block = (b, a, nhalf).
// M=128, N=256, K=512. A = relu(u[c]+v_a) staged in LDS (fragment order);
// B DMA'd via global_load_lds from pre-tiled swizzled w1t; double-buffered.
__global__ __launch_bounds__(256, 2)
void k_pair(const float* __restrict__ u, const float* __restrict__ v,
            const __bf16* __restrict__ w1t, const float* __restrict__ qterm,
            float* __restrict__ xg) {
    __shared__ float  v_a[512];
    __shared__ __bf16 At[2][4096];     // [buf][mtile(8)][lane(64)*8]
    __shared__ __bf16 Bt[2][8192];     // [buf][n_local(256)][32k swizzled]
    __shared__ float  ebuf[4][128];

    const int bid  = blockIdx.x;
    const int b    = bid >> 8;
    const int a    = (bid >> 1) & 127;
    const int nbase = (bid & 1) << 8;
    const int tid  = threadIdx.x;
    const int wave = tid >> 6, lane = tid & 63;
    const int quad = lane >> 4, l15 = lane & 15;
    const int nloc = (wave >> 1) * 128;    // wave's n offset within [0,256)
    const int mtg  = (wave & 1) * 4;       // wave's mtile base
    const int swz  = (l15 >> 1) & 3;

    if (tid < 128)
        *(float4*)(v_a + tid * 4) = *(const float4*)(v + (b * D_ + a) * G0P + tid * 4);

    // B staging: wave issues 4 DMA instrs, instr j covers n_local [(wave*4+j)*16,+16)
    const int iw0 = wave * 4;
    const __bf16* gsrc = w1t + (size_t)(nbase + iw0 * 16 + (lane >> 2)) * 32
                             + (lane & 3) * 8;

    // A staging geometry: thread -> (m = tid>>1, k-off = (tid&1)*16)
    const int sm = tid >> 1;
    const int sk = (tid & 1) << 4;
    const float* urow = u + (b * D_ + sm) * G0P + sk;
    const int woff = (sm >> 4) * 512 + (sk >> 3) * 128 + (sm & 15) * 8;

    f32x4 acc[4][8];
    #pragma unroll
    for (int mt = 0; mt < 4; ++mt)
        #pragma unroll
        for (int nt = 0; nt < 8; ++nt)
            acc[mt][nt] = (f32x4){0.f, 0.f, 0.f, 0.f};

    float4 u0, u1, u2, u3;
    auto load_u = [&](int kq) {
        const float* p = urow + kq * 32;
        u0 = *(const float4*)p;       u1 = *(const float4*)(p + 4);
        u2 = *(const float4*)(p + 8); u3 = *(const float4*)(p + 12);
    };
    auto stage_B = [&](int buf, int kq) {
        const __bf16* g = gsrc + kq * 16384;
        __bf16* l = &Bt[buf][iw0 * 512];
        #pragma unroll
        for (int j = 0; j < 4; ++j)
            GL2LDS(g + j * 512, l + j * 512);
    };
    auto write_A = [&](int buf, int kq) {
        const float* vp = v_a + kq * 32 + sk;
        const float4 v0 = *(const float4*)vp,       v1 = *(const float4*)(vp + 4);
        const float4 v2 = *(const float4*)(vp + 8), v3 = *(const float4*)(vp + 12);
        bf16x8 h0, h1;
        h0[0] = (__bf16)fmaxf(u0.x + v0.x, 0.f);
        h0[1] = (__bf16)fmaxf(u0.y + v0.y, 0.f);
        h0[2] = (__bf16)fmaxf(u0.z + v0.z, 0.f);
        h0[3] = (__bf16)fmaxf(u0.w + v0.w, 0.f);
        h0[4] = (__bf16)fmaxf(u1.x + v1.x, 0.f);
        h0[5] = (__bf16)fmaxf(u1.y + v1.y, 0.f);
        h0[6] = (__bf16)fmaxf(u1.z + v1.z, 0.f);
        h0[7] = (__bf16)fmaxf(u1.w + v1.w, 0.f);
        h1[0] = (__bf16)fmaxf(u2.x + v2.x, 0.f);
        h1[1] = (__bf16)fmaxf(u2.y + v2.y, 0.f);
        h1[2] = (__bf16)fmaxf(u2.z + v2.z, 0.f);
        h1[3] = (__bf16)fmaxf(u2.w + v2.w, 0.f);
        h1[4] = (__bf16)fmaxf(u3.x + v3.x, 0.f);
        h1[5] = (__bf16)fmaxf(u3.y + v3.y, 0.f);
        h1[6] = (__bf16)fmaxf(u3.z + v3.z, 0.f);
        h1[7] = (__bf16)fmaxf(u3.w + v3.w, 0.f);
        __bf16* w = &At[buf][woff];
        *(bf16x8*)w = h0;
        *(bf16x8*)(w + 128) = h1;
    };

    // prologue
    stage_B(0, 0);
    load_u(0);
    __syncthreads();               // v_a visible, Bt[0] DMA drained
    write_A(0, 0);
    __syncthreads();               // At[0] visible

    for (int kq = 0; kq < 16; ++kq) {
        const int buf = kq & 1;
        if (kq < 15) {
            stage_B(buf ^ 1, kq + 1);      // async DMA into other buffer
            load_u(kq + 1);                // u regs for next A tile
        }
        bf16x8 af[4];
        #pragma unroll
        for (int mt = 0; mt < 4; ++mt)
            af[mt] = *(const bf16x8*)&At[buf][(mtg + mt) * 512 + lane * 8];
        bf16x8 bfr[8];
        const __bf16* btb = &Bt[buf][(nloc + l15) * 32 + ((quad ^ swz) << 3)];
        #pragma unroll
        for (int nt = 0; nt < 8; ++nt)
            bfr[nt] = *(const bf16x8*)(btb + nt * 512);
        #pragma unroll
        for (int mt = 0; mt < 4; ++mt)
            #pragma unroll
            for (int nt = 0; nt < 8; ++nt)
                acc[mt][nt] = __builtin_amdgcn_mfma_f32_16x16x32_bf16(
                    af[mt], bfr[nt], acc[mt][nt], 0, 0, 0);
        if (kq < 15) write_A(buf ^ 1, kq + 1);
        __syncthreads();           // drains DMA + ds_writes for buf^1
    }

    // epilogue: relu(C + qterm), reduce over 64 m-rows per wave, combine, atomic
    #pragma unroll
    for (int nt = 0; nt < 8; ++nt) {
        const float q = qterm[b * G1_ + nbase + nloc + nt * 16 + l15];
        float s = 0.f;
        #pragma unroll
        for (int mt = 0; mt < 4; ++mt)
            #pragma unroll
            for (int r = 0; r < 4; ++r)
                s += fmaxf(acc[mt][nt][r] + q, 0.f);
        s += __shfl_xor(s, 16, 64);
        s += __shfl_xor(s, 32, 64);
        if (quad == 0) ebuf[wave][nt * 16 + l15] = s;
    }
    __syncthreads();
    {
        const int grp = tid >> 7, nl = tid & 127;
        atomicAdd(xg + b * G1_ + nbase + grp * 128 + nl,
                  ebuf[grp * 2][nl] + ebuf[grp * 2 + 1][nl]);
    }
}

// ---------------------------------------------------------------------------
// k_f12: f1 (redundant per block) + 32 f2 outputs per block.
// grid = 256 blocks = (b, og); block-local s1 via LDS; coalesced weight reads.
__global__ __launch_bounds__(256)
void k_f12(const float* __restrict__ xg,
           const float* __restrict__ f1w, const float* __restrict__ f1b,
           const float* __restrict__ f2w, const float* __restrict__ f2b,
           float* __restrict__ s2g) {
    const int b = blockIdx.x >> 5, og = blockIdx.x & 31;
    const int t = threadIdx.x;
    __shared__ float xs[G1_];
    __shared__ float s1[F1_];
    __shared__ float red[8][33];
    xs[t] = xg[b * G1_ + t];
    xs[t + 256] = xg[b * G1_ + 256 + t];
    __syncthreads();
    {
        float a0 = f1b[t], a1 = f1b[t + 256];
        #pragma unroll 8
        for (int k = 0; k < G1_; ++k) {
            const float xv = xs[k];
            a0 += xv * f1w[k * F1_ + t];
            a1 += xv * f1w[k * F1_ + t + 256];
        }
        s1[t] = fmaxf(a0, 0.f);
        s1[t + 256] = fmaxf(a1, 0.f);
    }
    __syncthreads();
    {
        const int o = og * 32 + (t & 31), ks = (t >> 5) * 64;
        float s = 0.f;
        #pragma unroll 8
        for (int j = 0; j < 64; ++j)
            s += s1[ks + j] * f2w[(ks + j) * F2_ + o];
        red[t >> 5][t & 31] = s;
    }
    __syncthreads();
    if (t < 32) {
        float a = f2b[og * 32 + t];
        #pragma unroll
        for (int i = 0; i < 8; ++i) a += red[i][t];
        s2g[b * F2_ + og * 32 + t] = fmaxf(a, 0.f);
    }
}

// ---------------------------------------------------------------------------
// k_f3: f3 + log_softmax, 8 blocks (one per batch).
__global__ __launch_bounds__(256)
void k_f3(const float* __restrict__ s2g, const float* __restrict__ f3w,
          const float* __restrict__ f3b, float* __restrict__ out) {
    const int b = blockIdx.x, t = threadIdx.x;
    __shared__ float s2[F2_];
    __shared__ float red[16][17];
    __shared__ float lg[16];
    #pragma unroll
    for (int i = 0; i < 4; ++i) s2[t + i * 256] = s2g[b * F2_ + t + i * 256];
    __syncthreads();
    {
        const int o = t & 15, ks = (t >> 4) * 64;
        float a = 0.f;
        #pragma unroll 8
        for (int j = 0; j < 64; ++j)
            a += s2[ks + j] * f3w[(ks + j) * OUT_ + o];
        red[t >> 4][o] = a;
    }
    __syncthreads();
    if (t < 16) {
        float a = f3b[t];
        #pragma unroll
        for (int i = 0; i < 16; ++i) a += red[i][t];
        lg[t] = a;
    }
    __syncthreads();
    if (t < 16) {
        float m = -1e30f;
        #pragma unroll
        for (int i = 0; i < 16; ++i) m = fmaxf(m, lg[i]);
        float se = 0.f;
        #pragma unroll
        for (int i = 0; i < 16; ++i) se += __expf(lg[i] - m);
        out[b * OUT_ + t] = lg[t] - m - logf(se);
    }
}

// ---------------------------------------------------------------------------
extern "C" void kernel_launch(void* const* d_in, const int* in_sizes, int n_in,
                              void* d_out, int out_size, void* d_ws, size_t ws_size,
                              hipStream_t stream) {
    const float* x   = (const float*)d_in[0];
    const float* qst = (const float*)d_in[1];
    const float* g0w = (const float*)d_in[2];
    const float* g0b = (const float*)d_in[3];
    const float* g1w = (const float*)d_in[4];
    const float* g1b = (const float*)d_in[5];
    const float* f1w = (const float*)d_in[6];
    const float* f1b = (const float*)d_in[7];
    const float* f2w = (const float*)d_in[8];
    const float* f2b = (const float*)d_in[9];
    const float* f3w = (const float*)d_in[10];
    const float* f3b = (const float*)d_in[11];

    char* ws = (char*)d_ws;
    float*  u     = (float*)ws;  ws += (size_t)B_ * D_ * G0P * 4;   // 2 MB
    float*  v     = (float*)ws;  ws += (size_t)B_ * D_ * G0P * 4;   // 2 MB
    __bf16* w1t   = (__bf16*)ws; ws += (size_t)G1_ * G0P * 2;       // 512 KB
    float*  qterm = (float*)ws;  ws += (size_t)B_ * G1_ * 4;
    float*  xg    = (float*)ws;  ws += (size_t)B_ * G1_ * 4;
    float*  s2g   = (float*)ws;  ws += (size_t)B_ * F2_ * 4;

    k_prep<<<1320, 256, 0, stream>>>(x, g0w, g0b, qst, g1w, g1b,
                                     u, v, w1t, qterm, xg);
    k_pair<<<B_ * D_ * 2, 256, 0, stream>>>(u, v, w1t, qterm, xg);
    k_f12 <<<256, 256, 0, stream>>>(xg, f1w, f1b, f2w, f2b, s2g);
    k_f3  <<<B_, 256, 0, stream>>>(s2g, f3w, f3b, (float*)d_out);
}